// Round 4
// baseline (250.840 us; speedup 1.0000x reference)
//
#include <hip/hip_runtime.h>
#include <stdint.h>
#include <stddef.h>

typedef _Float16 f16;
typedef _Float16 half8 __attribute__((ext_vector_type(8)));
typedef _Float16 half4 __attribute__((ext_vector_type(4)));
typedef float floatx4 __attribute__((ext_vector_type(4)));

__device__ __forceinline__ floatx4 mfma16(half8 a, half8 b, floatx4 c) {
    return __builtin_amdgcn_mfma_f32_16x16x32_f16(a, b, c, 0, 0, 0);
}

typedef __attribute__((address_space(3))) void       lds_void_t;
typedef const __attribute__((address_space(1))) void gconst_void_t;

// async 16B/lane global->LDS; lds dest = wave-uniform base + lane*16
__device__ __forceinline__ void async_copy16(void* lds, const void* g) {
    __builtin_amdgcn_global_load_lds((gconst_void_t*)g, (lds_void_t*)lds, 16, 0, 0);
}

// ---------------- fused pre-pass ----------------
// blocks [0,2048): convert x f32->f16 row-major
// blocks [2048,2816): transpose w_attn [1024,3072] -> wattnT [3072,1024] f16
// blocks [2816,3072): transpose w_proj [1024,1024] -> wprojT [1024,1024] f16
__global__ __launch_bounds__(256)
void prepass(const float* __restrict__ x, const float* __restrict__ w_attn,
             const float* __restrict__ w_proj,
             f16* __restrict__ xh, f16* __restrict__ wattnT, f16* __restrict__ wprojT)
{
    __shared__ __align__(16) f16 t[64][72];
    const int bid = blockIdx.x;
    if (bid < 2048) {
        const size_t i = ((size_t)bid * 256 + threadIdx.x) * 8;
        floatx4 a = *(const floatx4*)(x + i);
        floatx4 b = *(const floatx4*)(x + i + 4);
        half8 h;
        h[0]=(f16)a[0]; h[1]=(f16)a[1]; h[2]=(f16)a[2]; h[3]=(f16)a[3];
        h[4]=(f16)b[0]; h[5]=(f16)b[1]; h[6]=(f16)b[2]; h[7]=(f16)b[3];
        *(half8*)(xh + i) = h;
        return;
    }
    const float* W; f16* WT; int Nsz, bx, by;
    if (bid < 2816) {
        W = w_attn; WT = wattnT; Nsz = 3072;
        const int r = bid - 2048; by = r / 48; bx = r - by * 48;
    } else {
        W = w_proj; WT = wprojT; Nsz = 1024;
        const int r = bid - 2816; by = r >> 4; bx = r & 15;
    }
    const int k0 = by << 6;
    const int n0 = bx << 6;
    {
        const int r  = threadIdx.x >> 2;
        const int c0 = (threadIdx.x & 3) << 4;
        #pragma unroll
        for (int i = 0; i < 4; ++i) {
            const int c = c0 + (i << 2);
            floatx4 v = *(const floatx4*)(W + (size_t)(k0 + r) * Nsz + n0 + c);
            t[c + 0][r] = (f16)v[0];
            t[c + 1][r] = (f16)v[1];
            t[c + 2][r] = (f16)v[2];
            t[c + 3][r] = (f16)v[3];
        }
    }
    __syncthreads();
    {
        const int n  = threadIdx.x >> 2;
        const int kc = (threadIdx.x & 3) << 4;
        #pragma unroll
        for (int i = 0; i < 2; ++i) {
            half8 h = *(half8*)&t[n][kc + (i << 3)];
            *(half8*)(WT + (size_t)(n0 + n) * 1024 + k0 + kc + (i << 3)) = h;
        }
    }
}

// ---------------- QKV GEMM ----------------
// C = xh[4096,1024] @ wattnT[3072,1024]^T + b_attn -> per-head layouts:
//   Q,K: [bh][t][d]   V: [bh][d][t]
// R4: (a) double-buffered LDS, prefetch-at-top, vmcnt(0)+barrier AFTER compute
//     (hides the per-iter global latency the old stage->wait->compute order
//     exposed 32x); (b) Q/K blocks (n0<2048) use SWAPPED mfma operands so the
//     C-fragment holds 4 consecutive d at fixed t -> half4 packed stores
//     (4x fewer store instrs, no LDS restage); V blocks keep the original
//     order (fragment already packs 4 consecutive t -> half4 into V^T).
__global__ __launch_bounds__(256, 3)
void gemm_qkv(const f16* __restrict__ A, const f16* __restrict__ BT,
              const float* __restrict__ bias, f16* __restrict__ QKV)
{
    __shared__ __align__(16) f16 As[2][128 * 32];
    __shared__ __align__(16) f16 Bs[2][128 * 32];

    const int tid  = threadIdx.x;
    const int wave = tid >> 6;
    const int lane = tid & 63;
    const int quad = lane >> 4;
    const int l16  = lane & 15;
    const int wm   = (wave >> 1) * 64;
    const int wn   = (wave & 1) * 64;
    const int m0   = blockIdx.y * 128;
    const int n0   = blockIdx.x * 128;
    const int Ksz  = 1024;
    const bool isV = (n0 >= 2048);

    const int srow  = lane >> 2;
    const int skoff = (lane & 3) << 3;

    const f16* Ab = A  + (size_t)(m0 + wave * 16 + srow) * Ksz + skoff;
    const f16* Bb = BT + (size_t)(n0 + wave * 16 + srow) * Ksz + skoff;
    const size_t seg = (size_t)64 * Ksz;

    auto stage = [&](int buf, int kc) {
        f16* AsW = &As[buf][wave * 16 * 32];
        f16* BsW = &Bs[buf][wave * 16 * 32];
        async_copy16(AsW,           Ab + kc);
        async_copy16(AsW + 64 * 32, Ab + kc + seg);
        async_copy16(BsW,           Bb + kc);
        async_copy16(BsW + 64 * 32, Bb + kc + seg);
    };

    floatx4 acc[4][4] = {};

    stage(0, 0);
    asm volatile("s_waitcnt vmcnt(0)" ::: "memory");
    __syncthreads();

    int buf = 0;
    for (int kc = 0; kc < Ksz; kc += 32) {
        if (kc + 32 < Ksz) stage(buf ^ 1, kc + 32);   // prefetch next tile

        half8 a[4], b[4];
        #pragma unroll
        for (int mt = 0; mt < 4; ++mt)
            a[mt] = *(const half8*)&As[buf][(wm + mt * 16 + l16) * 32 + (quad << 3)];
        #pragma unroll
        for (int nt = 0; nt < 4; ++nt)
            b[nt] = *(const half8*)&Bs[buf][(wn + nt * 16 + l16) * 32 + (quad << 3)];
        if (!isV) {   // swapped: acc holds C^T (rows=d, cols=t)
            #pragma unroll
            for (int mt = 0; mt < 4; ++mt)
                #pragma unroll
                for (int nt = 0; nt < 4; ++nt)
                    acc[mt][nt] = mfma16(b[nt], a[mt], acc[mt][nt]);
        } else {
            #pragma unroll
            for (int mt = 0; mt < 4; ++mt)
                #pragma unroll
                for (int nt = 0; nt < 4; ++nt)
                    acc[mt][nt] = mfma16(a[mt], b[nt], acc[mt][nt]);
        }

        asm volatile("s_waitcnt vmcnt(0)" ::: "memory");  // prefetch landed (issued pre-compute)
        __syncthreads();
        buf ^= 1;
    }

    const size_t HSZ = (size_t)32 * 2048 * 64;   // one of Q/K/V regions
    if (!isV) {
        // swapped layout: lane holds t = m0+wm+mt*16+l16 fixed,
        // cols = n0+wn+nt*16+quad*4 + r (4 consecutive d within one head)
        #pragma unroll
        for (int mt = 0; mt < 4; ++mt) {
            const int tg = m0 + wm + mt * 16 + l16;
            const int bb = tg >> 11;
            const int t0 = tg & 2047;
            #pragma unroll
            for (int nt = 0; nt < 4; ++nt) {
                const int colbase = n0 + wn + nt * 16 + (quad << 2);
                const floatx4 bv = *(const floatx4*)(bias + colbase);
                const int reg = colbase >> 10;        // 0 = Q, 1 = K
                const int hh  = (colbase >> 6) & 15;
                const int d0  = colbase & 63;
                half4 h;
                h[0] = (f16)(acc[mt][nt][0] + bv[0]);
                h[1] = (f16)(acc[mt][nt][1] + bv[1]);
                h[2] = (f16)(acc[mt][nt][2] + bv[2]);
                h[3] = (f16)(acc[mt][nt][3] + bv[3]);
                *(half4*)(QKV + (size_t)reg * HSZ
                          + (((size_t)(bb * 16 + hh) * 2048 + t0) << 6) + d0) = h;
            }
        }
    } else {
        // original layout: lane holds col=d fixed, 4 consecutive t -> V^T half4
        #pragma unroll
        for (int mt = 0; mt < 4; ++mt) {
            #pragma unroll
            for (int nt = 0; nt < 4; ++nt) {
                const int col  = n0 + wn + nt * 16 + l16;
                const float bv = bias[col];
                const int row0 = m0 + wm + mt * 16 + (quad << 2);
                const int bb   = row0 >> 11;
                const int t0   = row0 & 2047;
                const int hh   = (col >> 6) & 15;
                const int d    = col & 63;
                half4 h;
                h[0] = (f16)(acc[mt][nt][0] + bv);
                h[1] = (f16)(acc[mt][nt][1] + bv);
                h[2] = (f16)(acc[mt][nt][2] + bv);
                h[3] = (f16)(acc[mt][nt][3] + bv);
                *(half4*)(QKV + 2 * HSZ
                          + (((size_t)(bb * 16 + hh) << 6) + d) * 2048 + t0) = h;
            }
        }
    }
}

// ---------------- proj GEMM: 128x64 tile (512 blocks = 2/CU) ----------------
// R4: dbuf+prefetch K-loop; swapped operands -> float4 C stores.
__global__ __launch_bounds__(256, 2)
void gemm_proj(const f16* __restrict__ A, const f16* __restrict__ BT,
               const float* __restrict__ bias, float* __restrict__ C)
{
    __shared__ __align__(16) f16 As[2][128 * 32];
    __shared__ __align__(16) f16 Bs[2][64 * 32];

    const int tid  = threadIdx.x;
    const int wave = tid >> 6;
    const int lane = tid & 63;
    const int quad = lane >> 4;
    const int l16  = lane & 15;
    const int wm   = (wave >> 1) * 64;
    const int wn   = (wave & 1) * 32;
    const int m0   = blockIdx.y * 128;
    const int n0   = blockIdx.x * 64;
    const int Ksz  = 1024;

    const int srow  = lane >> 2;
    const int skoff = (lane & 3) << 3;

    const f16* Ab = A  + (size_t)(m0 + wave * 16 + srow) * Ksz + skoff;
    const f16* Bb = BT + (size_t)(n0 + wave * 16 + srow) * Ksz + skoff;
    const size_t seg = (size_t)64 * Ksz;

    auto stage = [&](int buf, int kc) {
        f16* AsW = &As[buf][wave * 16 * 32];
        f16* BsW = &Bs[buf][wave * 16 * 32];
        async_copy16(AsW,           Ab + kc);
        async_copy16(AsW + 64 * 32, Ab + kc + seg);
        async_copy16(BsW,           Bb + kc);
    };

    floatx4 acc[4][2] = {};

    stage(0, 0);
    asm volatile("s_waitcnt vmcnt(0)" ::: "memory");
    __syncthreads();

    int buf = 0;
    for (int kc = 0; kc < Ksz; kc += 32) {
        if (kc + 32 < Ksz) stage(buf ^ 1, kc + 32);

        half8 a[4], b[2];
        #pragma unroll
        for (int mt = 0; mt < 4; ++mt)
            a[mt] = *(const half8*)&As[buf][(wm + mt * 16 + l16) * 32 + (quad << 3)];
        #pragma unroll
        for (int nt = 0; nt < 2; ++nt)
            b[nt] = *(const half8*)&Bs[buf][(wn + nt * 16 + l16) * 32 + (quad << 3)];
        #pragma unroll
        for (int mt = 0; mt < 4; ++mt)
            #pragma unroll
            for (int nt = 0; nt < 2; ++nt)
                acc[mt][nt] = mfma16(b[nt], a[mt], acc[mt][nt]);   // swapped -> C^T frag

        asm volatile("s_waitcnt vmcnt(0)" ::: "memory");
        __syncthreads();
        buf ^= 1;
    }

    #pragma unroll
    for (int mt = 0; mt < 4; ++mt) {
        const int tg = m0 + wm + mt * 16 + l16;
        #pragma unroll
        for (int nt = 0; nt < 2; ++nt) {
            const int colbase = n0 + wn + nt * 16 + (quad << 2);
            const floatx4 bv = *(const floatx4*)(bias + colbase);
            floatx4 v;
            v[0] = acc[mt][nt][0] + bv[0];
            v[1] = acc[mt][nt][1] + bv[1];
            v[2] = acc[mt][nt][2] + bv[2];
            v[3] = acc[mt][nt][3] + bv[3];
            *(floatx4*)(C + (size_t)tg * 1024 + colbase) = v;
        }
    }
}

// ---------------- Flash attention, causal (R2 best-known: 73.4us) ----------------
// Grid (32, 16): blockIdx.x = bh in [0,32) (FASTEST -> linear%8 = bh%8: all 16
// blocks of a head on one XCD; 4 heads/XCD = 2MB K/V resident in 4MB L2).
// Block does q-blocks j=pid and 31-pid (33 chunks, balanced; 512 blocks = 2/CU).
// Barrier every TWO chunks (Vt 4-buf, V-DMA issued 2 ahead at pair top);
// s_setprio(1) around MFMA clusters.
__global__ __launch_bounds__(256, 2)
void attn_fwd(const f16* __restrict__ Qb, const f16* __restrict__ Kb,
              const f16* __restrict__ Vb, f16* __restrict__ attn_out)
{
    const int bh   = blockIdx.x;     // 0..31
    const int pid  = blockIdx.y;     // 0..15
    const int head = bh & 15;
    const int b    = bh >> 4;
    const int tid  = threadIdx.x;
    const int wave = tid >> 6;
    const int lane = tid & 63;
    const int quad = lane >> 4;
    const int l16  = lane & 15;

    __shared__ __align__(16) f16 Vt[4][64 * 64];   // [buf][d][kv], kv chunk8 ^ (d&7)
    __shared__ __align__(16) f16 Ps[4][16 * 64];   // per-wave P[q][kv], same swizzle

    const f16* Qh = Qb + ((size_t)bh << 17);
    const f16* Kh = Kb + ((size_t)bh << 17);
    const f16* Vh = Vb + ((size_t)bh << 17);

    // V DMA: wave stages d rows 16w..16w+15; instr g covers rows +8g..+8g+7.
    // lane L -> d-row r8=L>>3, source kv-chunk c8=(L&7)^r8 (XOR-swizzled LDS).
    const int r8 = lane >> 3;
    const int c8 = (lane & 7) ^ r8;
    const f16* vsrcA = Vh + (size_t)(wave * 16 + r8) * 2048 + c8 * 8;
    const f16* vsrcB = vsrcA + (size_t)8 * 2048;

    half8 kf[8], kn[8];
    half8 qf0, qf1;
    floatx4 o[4];
    float lp;
    int qrow0;

    auto loadK = [&](int kv0, half8* dst) {
        const f16* kp = Kh + (size_t)(kv0 + l16) * 64 + (quad << 3);
        #pragma unroll
        for (int t = 0; t < 4; ++t) {
            dst[2 * t]     = *(const half8*)(kp + t * 16 * 64);
            dst[2 * t + 1] = *(const half8*)(kp + t * 16 * 64 + 32);
        }
    };
    auto dmaV = [&](int kv0, int buf) {
        async_copy16(&Vt[buf][(wave * 16) * 64],     vsrcA + kv0);
        async_copy16(&Vt[buf][(wave * 16 + 8) * 64], vsrcB + kv0);
    };

    const int sw = l16 & 7;   // swizzle key (= d&7 and q&7 for our rows)

    // one 64-kv chunk: QK^T -> softmax -> PV. No barrier inside.
    auto compute = [&](int kc, int j, half8* kcur) {
        floatx4 s[4] = {};
        __builtin_amdgcn_s_setprio(1);
        #pragma unroll
        for (int t = 0; t < 4; ++t) {
            s[t] = mfma16(kcur[2 * t],     qf0, s[t]);
            s[t] = mfma16(kcur[2 * t + 1], qf1, s[t]);
        }
        __builtin_amdgcn_s_setprio(0);
        const bool diag = (kc == j);
        const int qrel = (wave << 4) + l16;
        #pragma unroll
        for (int t = 0; t < 4; ++t) {
            float p0 = __builtin_amdgcn_exp2f(s[t][0]);
            float p1 = __builtin_amdgcn_exp2f(s[t][1]);
            float p2 = __builtin_amdgcn_exp2f(s[t][2]);
            float p3 = __builtin_amdgcn_exp2f(s[t][3]);
            if (diag) {
                const int kvb = t * 16 + (quad << 2);
                p0 = (kvb     <= qrel) ? p0 : 0.f;
                p1 = (kvb + 1 <= qrel) ? p1 : 0.f;
                p2 = (kvb + 2 <= qrel) ? p2 : 0.f;
                p3 = (kvb + 3 <= qrel) ? p3 : 0.f;
            }
            lp += (p0 + p1) + (p2 + p3);
            half4 pk; pk[0]=(f16)p0; pk[1]=(f16)p1; pk[2]=(f16)p2; pk[3]=(f16)p3;
            const int c = t * 2 + (quad >> 1);
            *(half4*)&Ps[wave][(l16 << 6) + ((c ^ sw) << 3) + ((quad & 1) << 2)] = pk;
        }
        asm volatile("s_waitcnt lgkmcnt(0)" ::: "memory");
        half8 pf0 = *(const half8*)&Ps[wave][(l16 << 6) + (((quad    ) ^ sw) << 3)];
        half8 pf1 = *(const half8*)&Ps[wave][(l16 << 6) + (((quad + 4) ^ sw) << 3)];
        const f16* vbuf = &Vt[kc & 3][0];
        __builtin_amdgcn_s_setprio(1);
        #pragma unroll
        for (int dt = 0; dt < 4; ++dt) {
            const f16* vrow = vbuf + ((dt * 16 + l16) << 6);
            half8 vf0 = *(const half8*)(vrow + (((quad    ) ^ sw) << 3));
            half8 vf1 = *(const half8*)(vrow + (((quad + 4) ^ sw) << 3));
            o[dt] = mfma16(pf0, vf0, o[dt]);
            o[dt] = mfma16(pf1, vf1, o[dt]);
        }
        __builtin_amdgcn_s_setprio(0);
    };

    auto pass = [&](int j) {
        qrow0 = j * 64 + wave * 16;
        {
            const f16* qp = Qh + (size_t)(qrow0 + l16) * 64 + (quad << 3);
            qf0 = *(const half8*)qp;
            qf1 = *(const half8*)(qp + 32);
        }
        const f16 qs = (f16)0.1803368801f;   // (1/8) * log2(e)
        #pragma unroll
        for (int i = 0; i < 8; ++i) { qf0[i] *= qs; qf1[i] *= qs; }
        o[0] = o[1] = o[2] = o[3] = (floatx4){0.f, 0.f, 0.f, 0.f};
        lp = 0.f;

        const int n = j + 1;
        loadK(0, kf);
        dmaV(0, 0);
        if (1 < n) dmaV(1 << 6, 1);

        // pair loop: one barrier per TWO chunks. At pair top, DMA chunks kc+2/kc+3.
        for (int kc = 0; kc < n; kc += 2) {
            __syncthreads();
            if (kc + 2 < n) dmaV((kc + 2) << 6, (kc + 2) & 3);
            if (kc + 3 < n) dmaV((kc + 3) << 6, (kc + 3) & 3);
            if (kc + 1 < n) loadK((kc + 1) << 6, kn);
            compute(kc, j, kf);
            if (kc + 1 < n) {
                if (kc + 2 < n) loadK((kc + 2) << 6, kf);
                compute(kc + 1, j, kn);
            }
        }

        // epilogue: reduce l over quads, transpose inv via shuffles, write O
        float l = lp;
        l += __shfl_xor(l, 16);
        l += __shfl_xor(l, 32);
        const float inv = 1.f / l;
        #pragma unroll
        for (int r = 0; r < 4; ++r) {
            const float invr = __shfl(inv, (quad << 2) + r);
            const int row = (b << 11) + qrow0 + (quad << 2) + r;
            f16* op = attn_out + (size_t)row * 1024 + head * 64 + l16;
            #pragma unroll
            for (int dt = 0; dt < 4; ++dt)
                op[dt * 16] = (f16)(o[dt][r] * invr);
        }
        __syncthreads();   // protect Vt before next pass's prologue DMA
    };

    pass(pid);
    pass(31 - pid);
}

extern "C" void kernel_launch(void* const* d_in, const int* in_sizes, int n_in,
                              void* d_out, int out_size, void* d_ws, size_t ws_size,
                              hipStream_t stream)
{
    const float* x      = (const float*)d_in[0];
    const float* w_attn = (const float*)d_in[1];
    const float* b_attn = (const float*)d_in[2];
    const float* w_proj = (const float*)d_in[3];
    const float* b_proj = (const float*)d_in[4];
    float* y = (float*)d_out;

    f16* xh       = (f16*)d_ws;                         // [4096,1024]
    f16* wattnT   = xh + (size_t)4096 * 1024;           // [3072,1024]
    f16* wprojT   = wattnT + (size_t)3072 * 1024;       // [1024,1024]
    f16* qkv      = wprojT + (size_t)1024 * 1024;       // Q,K: [32][2048][64]; V: [32][64][2048]
    f16* attn_out = qkv + (size_t)3 * 32 * 2048 * 64;   // [4096,1024]

    const size_t HSZ = (size_t)32 * 2048 * 64;

    prepass<<<dim3(3072), dim3(256), 0, stream>>>(x, w_attn, w_proj, xh, wattnT, wprojT);
    gemm_qkv<<<dim3(24, 32), dim3(256), 0, stream>>>(xh, wattnT, b_attn, qkv);
    attn_fwd<<<dim3(32, 16), dim3(256), 0, stream>>>(qkv, qkv + HSZ, qkv + 2 * HSZ, attn_out);
    gemm_proj<<<dim3(16, 32), dim3(256), 0, stream>>>(attn_out, wprojT, b_proj, y);
}

// Round 5
// 210.128 us; speedup vs baseline: 1.1937x; 1.1937x over previous
//
#include <hip/hip_runtime.h>
#include <stdint.h>
#include <stddef.h>

typedef _Float16 f16;
typedef _Float16 half8 __attribute__((ext_vector_type(8)));
typedef _Float16 half4 __attribute__((ext_vector_type(4)));
typedef float floatx4 __attribute__((ext_vector_type(4)));

__device__ __forceinline__ floatx4 mfma16(half8 a, half8 b, floatx4 c) {
    return __builtin_amdgcn_mfma_f32_16x16x32_f16(a, b, c, 0, 0, 0);
}

typedef __attribute__((address_space(3))) void       lds_void_t;
typedef const __attribute__((address_space(1))) void gconst_void_t;

// async 16B/lane global->LDS; lds dest = wave-uniform base + lane*16
__device__ __forceinline__ void async_copy16(void* lds, const void* g) {
    __builtin_amdgcn_global_load_lds((gconst_void_t*)g, (lds_void_t*)lds, 16, 0, 0);
}

// ---------------- fused pre-pass ----------------
// blocks [0,2048): convert x f32->f16 row-major
// blocks [2048,2816): transpose w_attn [1024,3072] -> wattnT [3072,1024] f16
// blocks [2816,3072): transpose w_proj [1024,1024] -> wprojT [1024,1024] f16
__global__ __launch_bounds__(256)
void prepass(const float* __restrict__ x, const float* __restrict__ w_attn,
             const float* __restrict__ w_proj,
             f16* __restrict__ xh, f16* __restrict__ wattnT, f16* __restrict__ wprojT)
{
    __shared__ __align__(16) f16 t[64][72];
    const int bid = blockIdx.x;
    if (bid < 2048) {
        const size_t i = ((size_t)bid * 256 + threadIdx.x) * 8;
        floatx4 a = *(const floatx4*)(x + i);
        floatx4 b = *(const floatx4*)(x + i + 4);
        half8 h;
        h[0]=(f16)a[0]; h[1]=(f16)a[1]; h[2]=(f16)a[2]; h[3]=(f16)a[3];
        h[4]=(f16)b[0]; h[5]=(f16)b[1]; h[6]=(f16)b[2]; h[7]=(f16)b[3];
        *(half8*)(xh + i) = h;
        return;
    }
    const float* W; f16* WT; int Nsz, bx, by;
    if (bid < 2816) {
        W = w_attn; WT = wattnT; Nsz = 3072;
        const int r = bid - 2048; by = r / 48; bx = r - by * 48;
    } else {
        W = w_proj; WT = wprojT; Nsz = 1024;
        const int r = bid - 2816; by = r >> 4; bx = r & 15;
    }
    const int k0 = by << 6;
    const int n0 = bx << 6;
    {
        const int r  = threadIdx.x >> 2;
        const int c0 = (threadIdx.x & 3) << 4;
        #pragma unroll
        for (int i = 0; i < 4; ++i) {
            const int c = c0 + (i << 2);
            floatx4 v = *(const floatx4*)(W + (size_t)(k0 + r) * Nsz + n0 + c);
            t[c + 0][r] = (f16)v[0];
            t[c + 1][r] = (f16)v[1];
            t[c + 2][r] = (f16)v[2];
            t[c + 3][r] = (f16)v[3];
        }
    }
    __syncthreads();
    {
        const int n  = threadIdx.x >> 2;
        const int kc = (threadIdx.x & 3) << 4;
        #pragma unroll
        for (int i = 0; i < 2; ++i) {
            half8 h = *(half8*)&t[n][kc + (i << 3)];
            *(half8*)(WT + (size_t)(n0 + n) * 1024 + k0 + kc + (i << 3)) = h;
        }
    }
}

// ---------------- QKV GEMM ----------------
// C = xh[4096,1024] @ wattnT[3072,1024]^T + b_attn -> per-head layouts:
//   Q,K: [bh][t][d]   V: [bh][d][t]
// R5: proven R2 sync structure (stage -> vmcnt(0) -> barrier -> compute ->
// barrier) but BK=64: HALF the exposed-latency stalls (16 iters not 32),
// 32 MFMA/wave amortize each stall. Rows are now 128B (exact 32-bank alias),
// so T2 XOR chunk-swizzle (rule #21 both-sides): LDS slot (row,c) holds
// global 16B-chunk c^(row&7); DMA source per lane = ((lane&7)^(lane>>3))*8
// with linear LDS dest; fragment reads use ((kk*4+quad)^(l16&7)) -> 2
// lanes/bank (free). Predicts bank-conflicts 3.1M -> <0.5M.
__global__ __launch_bounds__(256, 2)
void gemm_qkv(const f16* __restrict__ A, const f16* __restrict__ BT,
              const float* __restrict__ bias, f16* __restrict__ QKV)
{
    __shared__ __align__(16) f16 As[128 * 64];
    __shared__ __align__(16) f16 Bs[128 * 64];

    const int tid  = threadIdx.x;
    const int wave = tid >> 6;
    const int lane = tid & 63;
    const int quad = lane >> 4;
    const int l16  = lane & 15;
    const int wm   = (wave >> 1) * 64;
    const int wn   = (wave & 1) * 64;
    const int m0   = blockIdx.y * 128;
    const int n0   = blockIdx.x * 128;
    const int Ksz  = 1024;

    // staging geometry: one async_copy16 covers 8 rows x 64 cols; lane ->
    // row lr=lane>>3, source chunk csw=(lane&7)^lr (XOR pre-swizzle).
    const int lr  = lane >> 3;
    const int csw = (lane & 7) ^ lr;

    const f16* AbS = A  + (size_t)(m0 + wave * 16 + lr) * Ksz + csw * 8;
    const f16* BbS = BT + (size_t)(n0 + wave * 16 + lr) * Ksz + csw * 8;
    f16* AsW = &As[(wave * 16) * 64];
    f16* BsW = &Bs[(wave * 16) * 64];

    auto stage = [&](int kc) {
        #pragma unroll
        for (int h = 0; h < 2; ++h)
            #pragma unroll
            for (int c = 0; c < 2; ++c) {
                const int ro = h * 64 + c * 8;   // row offset within wave's slices
                async_copy16(AsW + (size_t)ro * 64, AbS + (size_t)ro * Ksz + kc);
                async_copy16(BsW + (size_t)ro * 64, BbS + (size_t)ro * Ksz + kc);
            }
    };

    floatx4 acc[4][4] = {};

    for (int kc = 0; kc < Ksz; kc += 64) {
        stage(kc);
        asm volatile("s_waitcnt vmcnt(0)" ::: "memory");
        __syncthreads();

        #pragma unroll
        for (int kk = 0; kk < 2; ++kk) {
            half8 a[4], b[4];
            #pragma unroll
            for (int mt = 0; mt < 4; ++mt) {
                const int row = wm + mt * 16 + l16;
                a[mt] = *(const half8*)&As[row * 64 + ((((kk << 2) + quad) ^ (l16 & 7)) << 3)];
            }
            #pragma unroll
            for (int nt = 0; nt < 4; ++nt) {
                const int row = wn + nt * 16 + l16;
                b[nt] = *(const half8*)&Bs[row * 64 + ((((kk << 2) + quad) ^ (l16 & 7)) << 3)];
            }
            #pragma unroll
            for (int mt = 0; mt < 4; ++mt)
                #pragma unroll
                for (int nt = 0; nt < 4; ++nt)
                    acc[mt][nt] = mfma16(a[mt], b[nt], acc[mt][nt]);
        }
        __syncthreads();
    }

    const size_t HSZ = (size_t)32 * 2048 * 64;   // one of Q/K/V regions
    #pragma unroll
    for (int mt = 0; mt < 4; ++mt) {
        #pragma unroll
        for (int nt = 0; nt < 4; ++nt) {
            const int col  = n0 + wn + nt * 16 + l16;
            const float bv = bias[col];
            const int row0 = m0 + wm + mt * 16 + (quad << 2);
            const int bb   = row0 >> 11;
            const int t0   = row0 & 2047;
            const int hh   = (col >> 6) & 15;
            const int d    = col & 63;
            float v0 = acc[mt][nt][0] + bv;
            float v1 = acc[mt][nt][1] + bv;
            float v2 = acc[mt][nt][2] + bv;
            float v3 = acc[mt][nt][3] + bv;
            if (col < 2048) {   // Q or K: [bh][t][d]
                f16* dst = QKV + (size_t)(col >> 10) * HSZ
                         + (((size_t)(bb * 16 + hh) * 2048 + t0) << 6) + d;
                dst[0]   = (f16)v0;
                dst[64]  = (f16)v1;
                dst[128] = (f16)v2;
                dst[192] = (f16)v3;
            } else {            // V^T: [bh][d][t], 4 consecutive t -> half4
                half4 h; h[0]=(f16)v0; h[1]=(f16)v1; h[2]=(f16)v2; h[3]=(f16)v3;
                *(half4*)(QKV + 2 * HSZ
                          + (((size_t)(bb * 16 + hh) << 6) + d) * 2048 + t0) = h;
            }
        }
    }
}

// ---------------- proj GEMM: 128x64 tile (512 blocks = 2/CU) ----------------
__global__ __launch_bounds__(256, 2)
void gemm_proj(const f16* __restrict__ A, const f16* __restrict__ BT,
               const float* __restrict__ bias, float* __restrict__ C)
{
    __shared__ __align__(16) f16 As[128 * 32];
    __shared__ __align__(16) f16 Bs[64 * 32];

    const int tid  = threadIdx.x;
    const int wave = tid >> 6;
    const int lane = tid & 63;
    const int quad = lane >> 4;
    const int l16  = lane & 15;
    const int wm   = (wave >> 1) * 64;
    const int wn   = (wave & 1) * 32;
    const int m0   = blockIdx.y * 128;
    const int n0   = blockIdx.x * 64;
    const int Ksz  = 1024;

    const int srow  = lane >> 2;
    const int skoff = (lane & 3) << 3;

    const f16* Ab = A  + (size_t)(m0 + wave * 16 + srow) * Ksz + skoff;
    const f16* Bb = BT + (size_t)(n0 + wave * 16 + srow) * Ksz + skoff;
    f16* AsW = &As[wave * 16 * 32];
    f16* BsW = &Bs[wave * 16 * 32];
    const size_t seg = (size_t)64 * Ksz;

    floatx4 acc[4][2] = {};

    for (int kc = 0; kc < Ksz; kc += 32) {
        async_copy16(AsW,           Ab + kc);
        async_copy16(AsW + 64 * 32, Ab + kc + seg);
        async_copy16(BsW,           Bb + kc);
        asm volatile("s_waitcnt vmcnt(0)" ::: "memory");
        __syncthreads();

        half8 a[4], b[2];
        #pragma unroll
        for (int mt = 0; mt < 4; ++mt)
            a[mt] = *(const half8*)&As[(wm + mt * 16 + l16) * 32 + (quad << 3)];
        #pragma unroll
        for (int nt = 0; nt < 2; ++nt)
            b[nt] = *(const half8*)&Bs[(wn + nt * 16 + l16) * 32 + (quad << 3)];
        #pragma unroll
        for (int mt = 0; mt < 4; ++mt)
            #pragma unroll
            for (int nt = 0; nt < 2; ++nt)
                acc[mt][nt] = mfma16(a[mt], b[nt], acc[mt][nt]);
        __syncthreads();
    }

    #pragma unroll
    for (int mt = 0; mt < 4; ++mt) {
        #pragma unroll
        for (int nt = 0; nt < 2; ++nt) {
            const int col  = n0 + wn + nt * 16 + l16;
            const float bv = bias[col];
            #pragma unroll
            for (int r = 0; r < 4; ++r) {
                const int row = m0 + wm + mt * 16 + (quad << 2) + r;
                C[(size_t)row * 1024 + col] = acc[mt][nt][r] + bv;
            }
        }
    }
}

// ---------------- Flash attention, causal (R2 best-known: 73.4us) ----------------
// Grid (32, 16): blockIdx.x = bh in [0,32) (FASTEST -> linear%8 = bh%8: all 16
// blocks of a head on one XCD; 4 heads/XCD = 2MB K/V resident in 4MB L2).
// Block does q-blocks j=pid and 31-pid (33 chunks, balanced; 512 blocks = 2/CU).
// Barrier every TWO chunks (Vt 4-buf, V-DMA issued 2 ahead at pair top);
// s_setprio(1) around MFMA clusters.
__global__ __launch_bounds__(256, 2)
void attn_fwd(const f16* __restrict__ Qb, const f16* __restrict__ Kb,
              const f16* __restrict__ Vb, f16* __restrict__ attn_out)
{
    const int bh   = blockIdx.x;     // 0..31
    const int pid  = blockIdx.y;     // 0..15
    const int head = bh & 15;
    const int b    = bh >> 4;
    const int tid  = threadIdx.x;
    const int wave = tid >> 6;
    const int lane = tid & 63;
    const int quad = lane >> 4;
    const int l16  = lane & 15;

    __shared__ __align__(16) f16 Vt[4][64 * 64];   // [buf][d][kv], kv chunk8 ^ (d&7)
    __shared__ __align__(16) f16 Ps[4][16 * 64];   // per-wave P[q][kv], same swizzle

    const f16* Qh = Qb + ((size_t)bh << 17);
    const f16* Kh = Kb + ((size_t)bh << 17);
    const f16* Vh = Vb + ((size_t)bh << 17);

    // V DMA: wave stages d rows 16w..16w+15; instr g covers rows +8g..+8g+7.
    // lane L -> d-row r8=L>>3, source kv-chunk c8=(L&7)^r8 (XOR-swizzled LDS).
    const int r8 = lane >> 3;
    const int c8 = (lane & 7) ^ r8;
    const f16* vsrcA = Vh + (size_t)(wave * 16 + r8) * 2048 + c8 * 8;
    const f16* vsrcB = vsrcA + (size_t)8 * 2048;

    half8 kf[8], kn[8];
    half8 qf0, qf1;
    floatx4 o[4];
    float lp;
    int qrow0;

    auto loadK = [&](int kv0, half8* dst) {
        const f16* kp = Kh + (size_t)(kv0 + l16) * 64 + (quad << 3);
        #pragma unroll
        for (int t = 0; t < 4; ++t) {
            dst[2 * t]     = *(const half8*)(kp + t * 16 * 64);
            dst[2 * t + 1] = *(const half8*)(kp + t * 16 * 64 + 32);
        }
    };
    auto dmaV = [&](int kv0, int buf) {
        async_copy16(&Vt[buf][(wave * 16) * 64],     vsrcA + kv0);
        async_copy16(&Vt[buf][(wave * 16 + 8) * 64], vsrcB + kv0);
    };

    const int sw = l16 & 7;   // swizzle key (= d&7 and q&7 for our rows)

    // one 64-kv chunk: QK^T -> softmax -> PV. No barrier inside.
    auto compute = [&](int kc, int j, half8* kcur) {
        floatx4 s[4] = {};
        __builtin_amdgcn_s_setprio(1);
        #pragma unroll
        for (int t = 0; t < 4; ++t) {
            s[t] = mfma16(kcur[2 * t],     qf0, s[t]);
            s[t] = mfma16(kcur[2 * t + 1], qf1, s[t]);
        }
        __builtin_amdgcn_s_setprio(0);
        const bool diag = (kc == j);
        const int qrel = (wave << 4) + l16;
        #pragma unroll
        for (int t = 0; t < 4; ++t) {
            float p0 = __builtin_amdgcn_exp2f(s[t][0]);
            float p1 = __builtin_amdgcn_exp2f(s[t][1]);
            float p2 = __builtin_amdgcn_exp2f(s[t][2]);
            float p3 = __builtin_amdgcn_exp2f(s[t][3]);
            if (diag) {
                const int kvb = t * 16 + (quad << 2);
                p0 = (kvb     <= qrel) ? p0 : 0.f;
                p1 = (kvb + 1 <= qrel) ? p1 : 0.f;
                p2 = (kvb + 2 <= qrel) ? p2 : 0.f;
                p3 = (kvb + 3 <= qrel) ? p3 : 0.f;
            }
            lp += (p0 + p1) + (p2 + p3);
            half4 pk; pk[0]=(f16)p0; pk[1]=(f16)p1; pk[2]=(f16)p2; pk[3]=(f16)p3;
            const int c = t * 2 + (quad >> 1);
            *(half4*)&Ps[wave][(l16 << 6) + ((c ^ sw) << 3) + ((quad & 1) << 2)] = pk;
        }
        asm volatile("s_waitcnt lgkmcnt(0)" ::: "memory");
        half8 pf0 = *(const half8*)&Ps[wave][(l16 << 6) + (((quad    ) ^ sw) << 3)];
        half8 pf1 = *(const half8*)&Ps[wave][(l16 << 6) + (((quad + 4) ^ sw) << 3)];
        const f16* vbuf = &Vt[kc & 3][0];
        __builtin_amdgcn_s_setprio(1);
        #pragma unroll
        for (int dt = 0; dt < 4; ++dt) {
            const f16* vrow = vbuf + ((dt * 16 + l16) << 6);
            half8 vf0 = *(const half8*)(vrow + (((quad    ) ^ sw) << 3));
            half8 vf1 = *(const half8*)(vrow + (((quad + 4) ^ sw) << 3));
            o[dt] = mfma16(pf0, vf0, o[dt]);
            o[dt] = mfma16(pf1, vf1, o[dt]);
        }
        __builtin_amdgcn_s_setprio(0);
    };

    auto pass = [&](int j) {
        qrow0 = j * 64 + wave * 16;
        {
            const f16* qp = Qh + (size_t)(qrow0 + l16) * 64 + (quad << 3);
            qf0 = *(const half8*)qp;
            qf1 = *(const half8*)(qp + 32);
        }
        const f16 qs = (f16)0.1803368801f;   // (1/8) * log2(e)
        #pragma unroll
        for (int i = 0; i < 8; ++i) { qf0[i] *= qs; qf1[i] *= qs; }
        o[0] = o[1] = o[2] = o[3] = (floatx4){0.f, 0.f, 0.f, 0.f};
        lp = 0.f;

        const int n = j + 1;
        loadK(0, kf);
        dmaV(0, 0);
        if (1 < n) dmaV(1 << 6, 1);

        // pair loop: one barrier per TWO chunks. At pair top, DMA chunks kc+2/kc+3.
        for (int kc = 0; kc < n; kc += 2) {
            __syncthreads();
            if (kc + 2 < n) dmaV((kc + 2) << 6, (kc + 2) & 3);
            if (kc + 3 < n) dmaV((kc + 3) << 6, (kc + 3) & 3);
            if (kc + 1 < n) loadK((kc + 1) << 6, kn);
            compute(kc, j, kf);
            if (kc + 1 < n) {
                if (kc + 2 < n) loadK((kc + 2) << 6, kf);
                compute(kc + 1, j, kn);
            }
        }

        // epilogue: reduce l over quads, transpose inv via shuffles, write O
        float l = lp;
        l += __shfl_xor(l, 16);
        l += __shfl_xor(l, 32);
        const float inv = 1.f / l;
        #pragma unroll
        for (int r = 0; r < 4; ++r) {
            const float invr = __shfl(inv, (quad << 2) + r);
            const int row = (b << 11) + qrow0 + (quad << 2) + r;
            f16* op = attn_out + (size_t)row * 1024 + head * 64 + l16;
            #pragma unroll
            for (int dt = 0; dt < 4; ++dt)
                op[dt * 16] = (f16)(o[dt][r] * invr);
        }
        __syncthreads();   // protect Vt before next pass's prologue DMA
    };

    pass(pid);
    pass(31 - pid);
}

extern "C" void kernel_launch(void* const* d_in, const int* in_sizes, int n_in,
                              void* d_out, int out_size, void* d_ws, size_t ws_size,
                              hipStream_t stream)
{
    const float* x      = (const float*)d_in[0];
    const float* w_attn = (const float*)d_in[1];
    const float* b_attn = (const float*)d_in[2];
    const float* w_proj = (const float*)d_in[3];
    const float* b_proj = (const float*)d_in[4];
    float* y = (float*)d_out;

    f16* xh       = (f16*)d_ws;                         // [4096,1024]
    f16* wattnT   = xh + (size_t)4096 * 1024;           // [3072,1024]
    f16* wprojT   = wattnT + (size_t)3072 * 1024;       // [1024,1024]
    f16* qkv      = wprojT + (size_t)1024 * 1024;       // Q,K: [32][2048][64]; V: [32][64][2048]
    f16* attn_out = qkv + (size_t)3 * 32 * 2048 * 64;   // [4096,1024]

    const size_t HSZ = (size_t)32 * 2048 * 64;

    prepass<<<dim3(3072), dim3(256), 0, stream>>>(x, w_attn, w_proj, xh, wattnT, wprojT);
    gemm_qkv<<<dim3(24, 32), dim3(256), 0, stream>>>(xh, wattnT, b_attn, qkv);
    attn_fwd<<<dim3(32, 16), dim3(256), 0, stream>>>(qkv, qkv + HSZ, qkv + 2 * HSZ, attn_out);
    gemm_proj<<<dim3(16, 32), dim3(256), 0, stream>>>(attn_out, wprojT, b_proj, y);
}

// Round 6
// 190.951 us; speedup vs baseline: 1.3136x; 1.1004x over previous
//
#include <hip/hip_runtime.h>
#include <stdint.h>
#include <stddef.h>

typedef _Float16 f16;
typedef _Float16 half8 __attribute__((ext_vector_type(8)));
typedef _Float16 half4 __attribute__((ext_vector_type(4)));
typedef float floatx4 __attribute__((ext_vector_type(4)));

__device__ __forceinline__ floatx4 mfma16(half8 a, half8 b, floatx4 c) {
    return __builtin_amdgcn_mfma_f32_16x16x32_f16(a, b, c, 0, 0, 0);
}

typedef __attribute__((address_space(3))) void       lds_void_t;
typedef const __attribute__((address_space(1))) void gconst_void_t;

// async 16B/lane global->LDS; lds dest = wave-uniform base + lane*16
__device__ __forceinline__ void async_copy16(void* lds, const void* g) {
    __builtin_amdgcn_global_load_lds((gconst_void_t*)g, (lds_void_t*)lds, 16, 0, 0);
}

// ---------------- fused pre-pass ----------------
// blocks [0,2048): convert x f32->f16 row-major
// blocks [2048,2816): transpose w_attn [1024,3072] -> wattnT [3072,1024] f16
// blocks [2816,3072): transpose w_proj [1024,1024] -> wprojT [1024,1024] f16
__global__ __launch_bounds__(256)
void prepass(const float* __restrict__ x, const float* __restrict__ w_attn,
             const float* __restrict__ w_proj,
             f16* __restrict__ xh, f16* __restrict__ wattnT, f16* __restrict__ wprojT)
{
    __shared__ __align__(16) f16 t[64][72];
    const int bid = blockIdx.x;
    if (bid < 2048) {
        const size_t i = ((size_t)bid * 256 + threadIdx.x) * 8;
        floatx4 a = *(const floatx4*)(x + i);
        floatx4 b = *(const floatx4*)(x + i + 4);
        half8 h;
        h[0]=(f16)a[0]; h[1]=(f16)a[1]; h[2]=(f16)a[2]; h[3]=(f16)a[3];
        h[4]=(f16)b[0]; h[5]=(f16)b[1]; h[6]=(f16)b[2]; h[7]=(f16)b[3];
        *(half8*)(xh + i) = h;
        return;
    }
    const float* W; f16* WT; int Nsz, bx, by;
    if (bid < 2816) {
        W = w_attn; WT = wattnT; Nsz = 3072;
        const int r = bid - 2048; by = r / 48; bx = r - by * 48;
    } else {
        W = w_proj; WT = wprojT; Nsz = 1024;
        const int r = bid - 2816; by = r >> 4; bx = r & 15;
    }
    const int k0 = by << 6;
    const int n0 = bx << 6;
    {
        const int r  = threadIdx.x >> 2;
        const int c0 = (threadIdx.x & 3) << 4;
        #pragma unroll
        for (int i = 0; i < 4; ++i) {
            const int c = c0 + (i << 2);
            floatx4 v = *(const floatx4*)(W + (size_t)(k0 + r) * Nsz + n0 + c);
            t[c + 0][r] = (f16)v[0];
            t[c + 1][r] = (f16)v[1];
            t[c + 2][r] = (f16)v[2];
            t[c + 3][r] = (f16)v[3];
        }
    }
    __syncthreads();
    {
        const int n  = threadIdx.x >> 2;
        const int kc = (threadIdx.x & 3) << 4;
        #pragma unroll
        for (int i = 0; i < 2; ++i) {
            half8 h = *(half8*)&t[n][kc + (i << 3)];
            *(half8*)(WT + (size_t)(n0 + n) * 1024 + k0 + kc + (i << 3)) = h;
        }
    }
}

// ---------------- QKV GEMM (R2-exact, proven) ----------------
// C = xh[4096,1024] @ wattnT[3072,1024]^T + b_attn, written to per-head layouts:
//   Q: [bh][t][d]  K: [bh][t][d]  V: [bh][d][t] (transposed, packed half4 stores)
// m97 structure: global_load_lds(16B) into unpadded [row][32] LDS, 2-barrier K-loop.
__global__ __launch_bounds__(256, 2)
void gemm_qkv(const f16* __restrict__ A, const f16* __restrict__ BT,
              const float* __restrict__ bias, f16* __restrict__ QKV)
{
    __shared__ __align__(16) f16 As[128 * 32];
    __shared__ __align__(16) f16 Bs[128 * 32];

    const int tid  = threadIdx.x;
    const int wave = tid >> 6;
    const int lane = tid & 63;
    const int quad = lane >> 4;
    const int l16  = lane & 15;
    const int wm   = (wave >> 1) * 64;
    const int wn   = (wave & 1) * 64;
    const int m0   = blockIdx.y * 128;
    const int n0   = blockIdx.x * 128;
    const int Ksz  = 1024;

    const int srow  = lane >> 2;
    const int skoff = (lane & 3) << 3;

    const f16* Ab = A  + (size_t)(m0 + wave * 16 + srow) * Ksz + skoff;
    const f16* Bb = BT + (size_t)(n0 + wave * 16 + srow) * Ksz + skoff;
    f16* AsW = &As[wave * 16 * 32];
    f16* BsW = &Bs[wave * 16 * 32];
    const size_t seg = (size_t)64 * Ksz;

    floatx4 acc[4][4] = {};

    for (int kc = 0; kc < Ksz; kc += 32) {
        async_copy16(AsW,           Ab + kc);
        async_copy16(AsW + 64 * 32, Ab + kc + seg);
        async_copy16(BsW,           Bb + kc);
        async_copy16(BsW + 64 * 32, Bb + kc + seg);
        asm volatile("s_waitcnt vmcnt(0)" ::: "memory");
        __syncthreads();

        half8 a[4], b[4];
        #pragma unroll
        for (int mt = 0; mt < 4; ++mt)
            a[mt] = *(const half8*)&As[(wm + mt * 16 + l16) * 32 + (quad << 3)];
        #pragma unroll
        for (int nt = 0; nt < 4; ++nt)
            b[nt] = *(const half8*)&Bs[(wn + nt * 16 + l16) * 32 + (quad << 3)];
        #pragma unroll
        for (int mt = 0; mt < 4; ++mt)
            #pragma unroll
            for (int nt = 0; nt < 4; ++nt)
                acc[mt][nt] = mfma16(a[mt], b[nt], acc[mt][nt]);
        __syncthreads();
    }

    const size_t HSZ = (size_t)32 * 2048 * 64;   // one of Q/K/V regions
    #pragma unroll
    for (int mt = 0; mt < 4; ++mt) {
        #pragma unroll
        for (int nt = 0; nt < 4; ++nt) {
            const int col  = n0 + wn + nt * 16 + l16;
            const float bv = bias[col];
            const int row0 = m0 + wm + mt * 16 + (quad << 2);
            const int bb   = row0 >> 11;
            const int t0   = row0 & 2047;
            const int hh   = (col >> 6) & 15;
            const int d    = col & 63;
            float v0 = acc[mt][nt][0] + bv;
            float v1 = acc[mt][nt][1] + bv;
            float v2 = acc[mt][nt][2] + bv;
            float v3 = acc[mt][nt][3] + bv;
            if (col < 2048) {   // Q or K: [bh][t][d]
                f16* dst = QKV + (size_t)(col >> 10) * HSZ
                         + (((size_t)(bb * 16 + hh) * 2048 + t0) << 6) + d;
                dst[0]   = (f16)v0;
                dst[64]  = (f16)v1;
                dst[128] = (f16)v2;
                dst[192] = (f16)v3;
            } else {            // V^T: [bh][d][t], 4 consecutive t -> half4
                half4 h; h[0]=(f16)v0; h[1]=(f16)v1; h[2]=(f16)v2; h[3]=(f16)v3;
                *(half4*)(QKV + 2 * HSZ
                          + (((size_t)(bb * 16 + hh) << 6) + d) * 2048 + t0) = h;
            }
        }
    }
}

// ---------------- proj GEMM: 128x64 tile (512 blocks = 2/CU, R2-exact) --------
__global__ __launch_bounds__(256, 2)
void gemm_proj(const f16* __restrict__ A, const f16* __restrict__ BT,
               const float* __restrict__ bias, float* __restrict__ C)
{
    __shared__ __align__(16) f16 As[128 * 32];
    __shared__ __align__(16) f16 Bs[64 * 32];

    const int tid  = threadIdx.x;
    const int wave = tid >> 6;
    const int lane = tid & 63;
    const int quad = lane >> 4;
    const int l16  = lane & 15;
    const int wm   = (wave >> 1) * 64;
    const int wn   = (wave & 1) * 32;
    const int m0   = blockIdx.y * 128;
    const int n0   = blockIdx.x * 64;
    const int Ksz  = 1024;

    const int srow  = lane >> 2;
    const int skoff = (lane & 3) << 3;

    const f16* Ab = A  + (size_t)(m0 + wave * 16 + srow) * Ksz + skoff;
    const f16* Bb = BT + (size_t)(n0 + wave * 16 + srow) * Ksz + skoff;
    f16* AsW = &As[wave * 16 * 32];
    f16* BsW = &Bs[wave * 16 * 32];
    const size_t seg = (size_t)64 * Ksz;

    floatx4 acc[4][2] = {};

    for (int kc = 0; kc < Ksz; kc += 32) {
        async_copy16(AsW,           Ab + kc);
        async_copy16(AsW + 64 * 32, Ab + kc + seg);
        async_copy16(BsW,           Bb + kc);
        asm volatile("s_waitcnt vmcnt(0)" ::: "memory");
        __syncthreads();

        half8 a[4], b[2];
        #pragma unroll
        for (int mt = 0; mt < 4; ++mt)
            a[mt] = *(const half8*)&As[(wm + mt * 16 + l16) * 32 + (quad << 3)];
        #pragma unroll
        for (int nt = 0; nt < 2; ++nt)
            b[nt] = *(const half8*)&Bs[(wn + nt * 16 + l16) * 32 + (quad << 3)];
        #pragma unroll
        for (int mt = 0; mt < 4; ++mt)
            #pragma unroll
            for (int nt = 0; nt < 2; ++nt)
                acc[mt][nt] = mfma16(a[mt], b[nt], acc[mt][nt]);
        __syncthreads();
    }

    #pragma unroll
    for (int mt = 0; mt < 4; ++mt) {
        #pragma unroll
        for (int nt = 0; nt < 2; ++nt) {
            const int col  = n0 + wn + nt * 16 + l16;
            const float bv = bias[col];
            #pragma unroll
            for (int r = 0; r < 4; ++r) {
                const int row = m0 + wm + mt * 16 + (quad << 2) + r;
                C[(size_t)row * 1024 + col] = acc[mt][nt][r] + bv;
            }
        }
    }
}

// ---------------- Flash attention, causal — FUSED 2-Q-BLOCK SCAN ----------------
// R1 evidence: per-CU chunk rate is FIXED (~2650cy/chunk, independent of resident
// blocks) -> attn time = chunk-periods/CU x 2650cy. Reduce PERIODS, not period cost:
// fuse pass(jA=pid) and pass(jB=31-pid) into ONE K/V scan (kc=0..jB; q-tile A
// computed only while kc<=jA). Periods/block: 33 -> 32-pid; K/V loads shared by
// both q-tiles. yy->pid table (pid = yy<8 ? yy : 23-yy) makes the two blocks on
// one CU (linear ids i, i+256 -> same bh, yy & yy+8) get pids p and 15-p ->
// periods (32-p)+(17+p) = 49/CU vs 66/CU before (-26%).
// Everything else R2-proven: bh-fastest grid (XCD-confined K/V), Vt 4-buf DMA
// 2 ahead, barrier per 2 chunks, setprio around MFMA, swizzled V/P LDS.
__global__ __launch_bounds__(256, 2)
void attn_fwd(const f16* __restrict__ Qb, const f16* __restrict__ Kb,
              const f16* __restrict__ Vb, f16* __restrict__ attn_out)
{
    const int bh   = blockIdx.x;     // 0..31
    const int yy   = blockIdx.y;     // 0..15
    const int pid  = (yy < 8) ? yy : 23 - yy;   // CU-pairing: p with 15-p
    const int jA   = pid;            // 0..15  (short q-tile)
    const int jB   = 31 - pid;       // 16..31 (long q-tile)
    const int head = bh & 15;
    const int b    = bh >> 4;
    const int tid  = threadIdx.x;
    const int wave = tid >> 6;
    const int lane = tid & 63;
    const int quad = lane >> 4;
    const int l16  = lane & 15;

    __shared__ __align__(16) f16 Vt[4][64 * 64];   // [buf][d][kv], kv chunk8 ^ (d&7)
    __shared__ __align__(16) f16 Ps[4][16 * 64];   // per-wave P[q][kv], same swizzle

    const f16* Qh = Qb + ((size_t)bh << 17);
    const f16* Kh = Kb + ((size_t)bh << 17);
    const f16* Vh = Vb + ((size_t)bh << 17);

    // V DMA: wave stages d rows 16w..16w+15; instr g covers rows +8g..+8g+7.
    // lane L -> d-row r8=L>>3, source kv-chunk c8=(L&7)^r8 (XOR-swizzled LDS).
    const int r8 = lane >> 3;
    const int c8 = (lane & 7) ^ r8;
    const f16* vsrcA = Vh + (size_t)(wave * 16 + r8) * 2048 + c8 * 8;
    const f16* vsrcB = vsrcA + (size_t)8 * 2048;

    half8 kf[8], kn[8];
    half8 qA0, qA1, qB0, qB1;
    floatx4 oA[4], oB[4];
    float lpA, lpB;

    auto loadK = [&](int kv0, half8* dst) {
        const f16* kp = Kh + (size_t)(kv0 + l16) * 64 + (quad << 3);
        #pragma unroll
        for (int t = 0; t < 4; ++t) {
            dst[2 * t]     = *(const half8*)(kp + t * 16 * 64);
            dst[2 * t + 1] = *(const half8*)(kp + t * 16 * 64 + 32);
        }
    };
    auto dmaV = [&](int kv0, int buf) {
        async_copy16(&Vt[buf][(wave * 16) * 64],     vsrcA + kv0);
        async_copy16(&Vt[buf][(wave * 16 + 8) * 64], vsrcB + kv0);
    };

    const int sw = l16 & 7;   // swizzle key (= d&7 and q&7 for our rows)

    // one 64-kv chunk for one q-tile: QK^T -> softmax -> PV. No barrier inside.
    auto compute = [&](int kc, int j, half8* kcur,
                       const half8& q0, const half8& q1, floatx4* o, float& lp) {
        floatx4 s[4] = {};
        __builtin_amdgcn_s_setprio(1);
        #pragma unroll
        for (int t = 0; t < 4; ++t) {
            s[t] = mfma16(kcur[2 * t],     q0, s[t]);
            s[t] = mfma16(kcur[2 * t + 1], q1, s[t]);
        }
        __builtin_amdgcn_s_setprio(0);
        const bool diag = (kc == j);
        const int qrel = (wave << 4) + l16;
        #pragma unroll
        for (int t = 0; t < 4; ++t) {
            float p0 = __builtin_amdgcn_exp2f(s[t][0]);
            float p1 = __builtin_amdgcn_exp2f(s[t][1]);
            float p2 = __builtin_amdgcn_exp2f(s[t][2]);
            float p3 = __builtin_amdgcn_exp2f(s[t][3]);
            if (diag) {
                const int kvb = t * 16 + (quad << 2);
                p0 = (kvb     <= qrel) ? p0 : 0.f;
                p1 = (kvb + 1 <= qrel) ? p1 : 0.f;
                p2 = (kvb + 2 <= qrel) ? p2 : 0.f;
                p3 = (kvb + 3 <= qrel) ? p3 : 0.f;
            }
            lp += (p0 + p1) + (p2 + p3);
            half4 pk; pk[0]=(f16)p0; pk[1]=(f16)p1; pk[2]=(f16)p2; pk[3]=(f16)p3;
            const int c = t * 2 + (quad >> 1);
            *(half4*)&Ps[wave][(l16 << 6) + ((c ^ sw) << 3) + ((quad & 1) << 2)] = pk;
        }
        asm volatile("s_waitcnt lgkmcnt(0)" ::: "memory");
        half8 pf0 = *(const half8*)&Ps[wave][(l16 << 6) + (((quad    ) ^ sw) << 3)];
        half8 pf1 = *(const half8*)&Ps[wave][(l16 << 6) + (((quad + 4) ^ sw) << 3)];
        const f16* vbuf = &Vt[kc & 3][0];
        __builtin_amdgcn_s_setprio(1);
        #pragma unroll
        for (int dt = 0; dt < 4; ++dt) {
            const f16* vrow = vbuf + ((dt * 16 + l16) << 6);
            half8 vf0 = *(const half8*)(vrow + (((quad    ) ^ sw) << 3));
            half8 vf1 = *(const half8*)(vrow + (((quad + 4) ^ sw) << 3));
            o[dt] = mfma16(pf0, vf0, o[dt]);
            o[dt] = mfma16(pf1, vf1, o[dt]);
        }
        __builtin_amdgcn_s_setprio(0);
    };

    const f16 qs = (f16)0.1803368801f;   // (1/8) * log2(e)
    auto loadQ = [&](int j, half8& q0, half8& q1) {
        const f16* qp = Qh + (size_t)(j * 64 + wave * 16 + l16) * 64 + (quad << 3);
        q0 = *(const half8*)qp;
        q1 = *(const half8*)(qp + 32);
        #pragma unroll
        for (int i = 0; i < 8; ++i) { q0[i] *= qs; q1[i] *= qs; }
    };

    loadQ(jA, qA0, qA1);
    loadQ(jB, qB0, qB1);
    oA[0]=oA[1]=oA[2]=oA[3] = (floatx4){0.f,0.f,0.f,0.f};
    oB[0]=oB[1]=oB[2]=oB[3] = (floatx4){0.f,0.f,0.f,0.f};
    lpA = 0.f; lpB = 0.f;

    const int nB = jB + 1;   // >= 17
    loadK(0, kf);
    dmaV(0, 0);
    dmaV(64, 1);

    // pair loop: one barrier per TWO chunks; DMA chunks kc+2/kc+3 at pair top.
    // Both q-tiles consume the SAME kf/kn and Vt chunk (K/V traffic shared).
    for (int kc = 0; kc < nB; kc += 2) {
        __syncthreads();
        if (kc + 2 < nB) dmaV((kc + 2) << 6, (kc + 2) & 3);
        if (kc + 3 < nB) dmaV((kc + 3) << 6, (kc + 3) & 3);
        if (kc + 1 < nB) loadK((kc + 1) << 6, kn);
        compute(kc, jB, kf, qB0, qB1, oB, lpB);
        if (kc <= jA) compute(kc, jA, kf, qA0, qA1, oA, lpA);
        if (kc + 1 < nB) {
            if (kc + 2 < nB) loadK((kc + 2) << 6, kf);
            compute(kc + 1, jB, kn, qB0, qB1, oB, lpB);
            if (kc + 1 <= jA) compute(kc + 1, jA, kn, qA0, qA1, oA, lpA);
        }
    }

    // epilogue per q-tile: reduce l over quads, transpose inv via shuffles, write O
    auto writeO = [&](int j, floatx4* o, float lp) {
        float l = lp;
        l += __shfl_xor(l, 16);
        l += __shfl_xor(l, 32);
        const float inv = 1.f / l;
        const int qrow0 = j * 64 + wave * 16;
        #pragma unroll
        for (int r = 0; r < 4; ++r) {
            const float invr = __shfl(inv, (quad << 2) + r);
            const int row = (b << 11) + qrow0 + (quad << 2) + r;
            f16* op = attn_out + (size_t)row * 1024 + head * 64 + l16;
            #pragma unroll
            for (int dt = 0; dt < 4; ++dt)
                op[dt * 16] = (f16)(o[dt][r] * invr);
        }
    };
    writeO(jB, oB, lpB);
    writeO(jA, oA, lpA);
}

extern "C" void kernel_launch(void* const* d_in, const int* in_sizes, int n_in,
                              void* d_out, int out_size, void* d_ws, size_t ws_size,
                              hipStream_t stream)
{
    const float* x      = (const float*)d_in[0];
    const float* w_attn = (const float*)d_in[1];
    const float* b_attn = (const float*)d_in[2];
    const float* w_proj = (const float*)d_in[3];
    const float* b_proj = (const float*)d_in[4];
    float* y = (float*)d_out;

    f16* xh       = (f16*)d_ws;                         // [4096,1024]
    f16* wattnT   = xh + (size_t)4096 * 1024;           // [3072,1024]
    f16* wprojT   = wattnT + (size_t)3072 * 1024;       // [1024,1024]
    f16* qkv      = wprojT + (size_t)1024 * 1024;       // Q,K: [32][2048][64]; V: [32][64][2048]
    f16* attn_out = qkv + (size_t)3 * 32 * 2048 * 64;   // [4096,1024]

    const size_t HSZ = (size_t)32 * 2048 * 64;

    prepass<<<dim3(3072), dim3(256), 0, stream>>>(x, w_attn, w_proj, xh, wattnT, wprojT);
    gemm_qkv<<<dim3(24, 32), dim3(256), 0, stream>>>(xh, wattnT, b_attn, qkv);
    attn_fwd<<<dim3(32, 16), dim3(256), 0, stream>>>(qkv, qkv + HSZ, qkv + 2 * HSZ, attn_out);
    gemm_proj<<<dim3(16, 32), dim3(256), 0, stream>>>(attn_out, wprojT, b_proj, y);
}